// Round 9
// baseline (201.029 us; speedup 1.0000x reference)
//
#include <hip/hip_runtime.h>

typedef unsigned short ushort_t;
using bf16x8 = __attribute__((ext_vector_type(8))) short;
using f32x4 = __attribute__((ext_vector_type(4))) float;

#define KT 27
#define NV 65536

__device__ inline unsigned short f2bf(float f) {
  unsigned int u = __builtin_bit_cast(unsigned int, f);
  u += 0x7fffu + ((u >> 16) & 1u);
  return (unsigned short)(u >> 16);
}
__device__ inline float b2f(ushort_t u) {
  unsigned int x = ((unsigned int)u) << 16;
  return __builtin_bit_cast(float, x);
}

// compile-time loop: every iteration index is constexpr.
template <int I, int N, typename F>
__device__ __forceinline__ void static_for(F&& f) {
  if constexpr (I < N) {
    f.template operator()<I>();
    static_for<I + 1, N>(static_cast<F&&>(f));
  }
}

// merged prep: statsp+zrow zero (block 0), x fp32->bf16 (blocks 0..4095),
// W1,W2 [k][c][d] -> per-lane MFMA B frags for 16x16x32 (blocks 4096..4959).
// Fragment layout (m89-verified): B col = c3*16 + (l&15), k-chan = q*32 + (l>>4)*8 + j.
// Wf[(k*8 + q*4 + c3)*512 + l*8 + j] = bf16(W[k][q*32 + (l>>4)*8 + j][c3*16 + (l&15)])
__global__ __launch_bounds__(256) void k_prep(const float* __restrict__ x,
                                              const float* __restrict__ W1,
                                              const float* __restrict__ W2,
                                              ushort_t* __restrict__ xb,
                                              ushort_t* __restrict__ Wf1,
                                              ushort_t* __restrict__ Wf2,
                                              float* __restrict__ statsp) {
  int b = blockIdx.x;
  int t = threadIdx.x;
  if (b == 0) {                    // 256 stats floats + 256 floats of zero-row pad
    statsp[t] = 0.f;               // convs run after this dispatch
    statsp[256 + t] = 0.f;         // zrow: gather target for inactive taps
  }
  if (b < 4096) {
    int i = b * 256 + t;  // float4 index
    float4 v = ((const float4*)x)[i];
    ushort4 o;
    o.x = f2bf(v.x); o.y = f2bf(v.y); o.z = f2bf(v.z); o.w = f2bf(v.w);
    ((ushort4*)xb)[i] = o;
  } else {
    int e = (b - 4096) * 256 + t;  // < 221184 = 2 * 110592
    const float* W = W1; ushort_t* Wf = Wf1;
    if (e >= 110592) { e -= 110592; W = W2; Wf = Wf2; }
    int j = e & 7, l = (e >> 3) & 63, u = (e >> 9) & 7, k = e >> 12;  // k < 27
    int q = u >> 2, c3 = u & 3;
    int ch = q * 32 + (l >> 4) * 8 + j;
    int d = c3 * 16 + (l & 15);
    Wf[e] = f2bf(W[(k << 12) + (ch << 6) + d]);
  }
}

// Gather-GEMM conv, 16x16x32 MFMA, barrier-free K-loop, ZERO A-staging.
// TLP experiment (R7, resubmitted R9 with safe occupancy plumbing):
// six rounds of pipeline restructuring at a constant 8 waves/CU all land
// 44-59us; even a fully-serial latency model predicts ~12us -> limiter is
// shared miss-concurrency, not per-wave scheduling. Halve the tile:
// 16 rows/wave (16x16x32), 4096 waves, grid 1024, 4 blocks/CU = 16 waves/CU.
// R9 CHANGE vs R7: __launch_bounds__(256, 4) replaces the exact-pin
// amdgpu_waves_per_eu(4,4) attribute (suspected backend ICE source -> the
// repeated container failures; launch_bounds has spill-if-needed semantics).
// A-gather: 4 consecutive lanes cover one row contiguously (64B clusters).
// A frag (lane): row r15, chans q*32 + g4*8 .. +8 -> one 16B load per chunk.
// Inactive taps gather a 128B zero row (pointer select).
// Only LDS: per-wave rulebook rows + stats reduce (~9 KB/block).
template<bool OBF16>
__global__ __launch_bounds__(256, 4)
void k_conv(const ushort_t* __restrict__ src,  // [N][64] bf16
            const int* __restrict__ nbr,       // [N][27]
            const ushort_t* __restrict__ Wf,
            const ushort_t* __restrict__ zrow, // 1KB of zeros
            void* __restrict__ houtv,          // [N][64]
            float* __restrict__ gsum,
            float* __restrict__ gsq) {
  __shared__ int nb_l[4][16 * KT];                 // per-wave rulebook rows, 6.9 KB
  __shared__ float red[2][4][64];                  // stats reduce, 2 KB

  const int t = threadIdx.x;
  const int lane = t & 63;
  const int w = t >> 6;
  const int r15 = lane & 15;
  const int g4 = lane >> 4;                        // 0..3: k-subgroup / row-quad
  const int wbase = blockIdx.x * 64 + w * 16;      // this wave's 16 voxel rows

  int* nbw = &nb_l[w][0];
  {
    const int* nbg = nbr + wbase * KT;
    for (int e = lane; e < 16 * KT; e += 64) nbw[e] = nbg[e];  // wave-local: no barrier
  }

  f32x4 acc0 = {0,0,0,0}, acc1 = {0,0,0,0}, acc2 = {0,0,0,0}, acc3 = {0,0,0,0};

  struct ATap { bf16x8 q0, q1; };                          // 8 VGPRs, by-value only
  struct BTap { bf16x8 u0, u1, u2, u3, u4, u5, u6, u7; };  // 32 VGPRs, by-value only

  const ushort_t* srcl = src + g4 * 8;   // lane's k-subgroup offset folded into base
  const ushort_t* zl = zrow + g4 * 8;

  // A frags for tap k: row r15, chunk q covers channels q*32 + g4*8 .. +8
  auto ldA = [&](int k) -> ATap {
    int idx = nbw[r15 * KT + k];
    const ushort_t* p = (idx >= 0) ? (srcl + ((long)idx << 6)) : zl;
    ATap a;
    a.q0 = *(const bf16x8*)(p);
    a.q1 = *(const bf16x8*)(p + 32);
    return a;
  };
  auto ldB = [&](int k) -> BTap {
    const ushort_t* p = Wf + k * 4096 + lane * 8;
    BTap b;
    b.u0 = *(const bf16x8*)(p);
    b.u1 = *(const bf16x8*)(p + 512);
    b.u2 = *(const bf16x8*)(p + 1024);
    b.u3 = *(const bf16x8*)(p + 1536);
    b.u4 = *(const bf16x8*)(p + 2048);
    b.u5 = *(const bf16x8*)(p + 2560);
    b.u6 = *(const bf16x8*)(p + 3072);
    b.u7 = *(const bf16x8*)(p + 3584);
    return b;
  };
  auto compute = [&](ATap a, BTap b) {
    acc0 = __builtin_amdgcn_mfma_f32_16x16x32_bf16(a.q0, b.u0, acc0, 0, 0, 0);
    acc1 = __builtin_amdgcn_mfma_f32_16x16x32_bf16(a.q0, b.u1, acc1, 0, 0, 0);
    acc2 = __builtin_amdgcn_mfma_f32_16x16x32_bf16(a.q0, b.u2, acc2, 0, 0, 0);
    acc3 = __builtin_amdgcn_mfma_f32_16x16x32_bf16(a.q0, b.u3, acc3, 0, 0, 0);
    acc0 = __builtin_amdgcn_mfma_f32_16x16x32_bf16(a.q1, b.u4, acc0, 0, 0, 0);
    acc1 = __builtin_amdgcn_mfma_f32_16x16x32_bf16(a.q1, b.u5, acc1, 0, 0, 0);
    acc2 = __builtin_amdgcn_mfma_f32_16x16x32_bf16(a.q1, b.u6, acc2, 0, 0, 0);
    acc3 = __builtin_amdgcn_mfma_f32_16x16x32_bf16(a.q1, b.u7, acc3, 0, 0, 0);
  };

  // prologue: A taps 0..1 in flight (ring-3, depth-2), B tap 0
  ATap A0 = ldA(0), A1 = ldA(1), A2;
  BTap B0 = ldB(0), B1;

  // invariant at iter k: slot k%3 holds tap k, B(k&1) holds tap k.
  static_for<0, KT>([&]<int k>() {
    if constexpr (k + 2 < KT) {
      ATap tmp = ldA(k + 2);
      constexpr int s = (k + 2) % 3;
      if constexpr (s == 0) A0 = tmp;
      else if constexpr (s == 1) A1 = tmp;
      else A2 = tmp;
    }
    if constexpr (k + 1 < KT) {
      BTap tmp = ldB(k + 1);
      if constexpr (((k + 1) & 1) == 0) B0 = tmp; else B1 = tmp;
    }
    __builtin_amdgcn_sched_barrier(0);   // loads above may not sink past compute
    constexpr int c = k % 3;
    if constexpr (c == 0) { if constexpr ((k & 1) == 0) compute(A0, B0); else compute(A0, B1); }
    else if constexpr (c == 1) { if constexpr ((k & 1) == 0) compute(A1, B0); else compute(A1, B1); }
    else { if constexpr ((k & 1) == 0) compute(A2, B0); else compute(A2, B1); }
  });

  // epilogue: store h + fused per-channel stats
  // C/D (16x16): col = c3*16 + (lane&15), row = (lane>>4)*4 + reg  (m89-verified)
  const int orow0 = wbase + g4 * 4;
  float s0 = 0.f, s1 = 0.f, s2 = 0.f, s3 = 0.f;
  float q0 = 0.f, q1 = 0.f, q2 = 0.f, q3 = 0.f;
#pragma unroll
  for (int reg = 0; reg < 4; ++reg) {
    int row = orow0 + reg;
    float v0 = acc0[reg], v1 = acc1[reg], v2 = acc2[reg], v3 = acc3[reg];
    if (OBF16) {
      ushort_t* ho = (ushort_t*)houtv;
      ho[row * 64 + r15] = f2bf(v0);
      ho[row * 64 + 16 + r15] = f2bf(v1);
      ho[row * 64 + 32 + r15] = f2bf(v2);
      ho[row * 64 + 48 + r15] = f2bf(v3);
    } else {
      float* ho = (float*)houtv;
      ho[row * 64 + r15] = v0;
      ho[row * 64 + 16 + r15] = v1;
      ho[row * 64 + 32 + r15] = v2;
      ho[row * 64 + 48 + r15] = v3;
    }
    s0 += v0; q0 += v0 * v0;
    s1 += v1; q1 += v1 * v1;
    s2 += v2; q2 += v2 * v2;
    s3 += v3; q3 += v3 * v3;
  }
  // fold the 4 row-quads (g4 groups) -> lanes 0..15 hold per-col sums
  s0 += __shfl_xor(s0, 16, 64); s0 += __shfl_xor(s0, 32, 64);
  s1 += __shfl_xor(s1, 16, 64); s1 += __shfl_xor(s1, 32, 64);
  s2 += __shfl_xor(s2, 16, 64); s2 += __shfl_xor(s2, 32, 64);
  s3 += __shfl_xor(s3, 16, 64); s3 += __shfl_xor(s3, 32, 64);
  q0 += __shfl_xor(q0, 16, 64); q0 += __shfl_xor(q0, 32, 64);
  q1 += __shfl_xor(q1, 16, 64); q1 += __shfl_xor(q1, 32, 64);
  q2 += __shfl_xor(q2, 16, 64); q2 += __shfl_xor(q2, 32, 64);
  q3 += __shfl_xor(q3, 16, 64); q3 += __shfl_xor(q3, 32, 64);
  if (lane < 16) {
    red[0][w][lane] = s0; red[0][w][16 + lane] = s1;
    red[0][w][32 + lane] = s2; red[0][w][48 + lane] = s3;
    red[1][w][lane] = q0; red[1][w][16 + lane] = q1;
    red[1][w][32 + lane] = q2; red[1][w][48 + lane] = q3;
  }
  __syncthreads();   // only barrier in the kernel
  if (t < 128) {
    int which = t >> 6, c = t & 63;
    float v = red[which][0][c] + red[which][1][c] + red[which][2][c] + red[which][3][c];
    atomicAdd((which ? gsq : gsum) + c, v);
  }
}

// BN1 (inline params from raw stats) + ReLU on bf16 h1, writes bf16 for conv2's gather
__global__ __launch_bounds__(256) void k_bn_relu(const ushort_t* __restrict__ h,
                                                 const float* __restrict__ gsum,
                                                 const float* __restrict__ gsq,
                                                 const float* __restrict__ gamma,
                                                 const float* __restrict__ beta,
                                                 ushort_t* __restrict__ ob) {
  __shared__ float sc[64], sh[64];
  int t = threadIdx.x;
  if (t < 64) {
    float mean = gsum[t] * (1.f / NV);
    float var = gsq[t] * (1.f / NV) - mean * mean;
    float rs = rsqrtf(var + 1e-5f);
    float s = gamma[t] * rs;
    sc[t] = s;
    sh[t] = beta[t] - mean * s;
  }
  __syncthreads();
  int i = blockIdx.x * 256 + t;    // uint4 index = 8 bf16
  int c0 = (i & 7) * 8;
  uint4 v = ((const uint4*)h)[i];
  const ushort_t* pu = (const ushort_t*)&v;
  uint4 o;
  ushort_t* po = (ushort_t*)&o;
#pragma unroll
  for (int n = 0; n < 8; ++n)
    po[n] = f2bf(fmaxf(0.f, b2f(pu[n]) * sc[c0 + n] + sh[c0 + n]));
  ((uint4*)ob)[i] = o;
}

// BN2 (inline params) + residual + ReLU, fp32 out
__global__ __launch_bounds__(256) void k_final(const float* __restrict__ h,
                                               const float* __restrict__ x,
                                               const float* __restrict__ gsum,
                                               const float* __restrict__ gsq,
                                               const float* __restrict__ gamma,
                                               const float* __restrict__ beta,
                                               float* __restrict__ out) {
  __shared__ float sc[64], sh[64];
  int t = threadIdx.x;
  if (t < 64) {
    float mean = gsum[t] * (1.f / NV);
    float var = gsq[t] * (1.f / NV) - mean * mean;
    float rs = rsqrtf(var + 1e-5f);
    float s = gamma[t] * rs;
    sc[t] = s;
    sh[t] = beta[t] - mean * s;
  }
  __syncthreads();
  int i = blockIdx.x * 256 + t;
  int c0 = (i << 2) & 63;
  float4 v = ((const float4*)h)[i];
  float4 xv = ((const float4*)x)[i];
  float4 o;
  o.x = fmaxf(0.f, v.x * sc[c0]     + sh[c0]     + xv.x);
  o.y = fmaxf(0.f, v.y * sc[c0 + 1] + sh[c0 + 1] + xv.y);
  o.z = fmaxf(0.f, v.z * sc[c0 + 2] + sh[c0 + 2] + xv.z);
  o.w = fmaxf(0.f, v.w * sc[c0 + 3] + sh[c0 + 3] + xv.w);
  ((float4*)out)[i] = o;
}

extern "C" void kernel_launch(void* const* d_in, const int* in_sizes, int n_in,
                              void* d_out, int out_size, void* d_ws, size_t ws_size,
                              hipStream_t stream) {
  const float* x   = (const float*)d_in[0];
  const int*   nbr = (const int*)d_in[1];
  const float* W1  = (const float*)d_in[2];
  const float* g1  = (const float*)d_in[3];
  const float* b1  = (const float*)d_in[4];
  const float* W2  = (const float*)d_in[5];
  const float* g2  = (const float*)d_in[6];
  const float* b2  = (const float*)d_in[7];
  float* out = (float*)d_out;
  char* ws = (char*)d_ws;

  // workspace layout (bytes, 256-aligned), total ~42.8 MB (+2KB stats/zero pad)
  ushort_t* xb     = (ushort_t*)(ws);               // 8,388,608
  ushort_t* h1pre  = (ushort_t*)(ws + 8388608);     // 8,388,608 (bf16, pre-BN)
  ushort_t* h1post = (ushort_t*)(ws + 16777216);    // 8,388,608 (bf16, post-BN+ReLU)
  ushort_t* Wf1    = (ushort_t*)(ws + 25165824);    // 221,184 used
  ushort_t* Wf2    = (ushort_t*)(ws + 25608192);    // 221,184 used
  float*    h2raw  = (float*)(ws + 26050560);       // 16,777,216
  float*    statsp = (float*)(ws + 42827776);       // 512 floats (stats + zero row)
  float *gsum1 = statsp, *gsq1 = statsp + 64, *gsum2 = statsp + 128, *gsq2 = statsp + 192;
  const ushort_t* zrow = (const ushort_t*)(statsp + 256);  // 1KB of zeros

  k_prep<<<4960, 256, 0, stream>>>(x, W1, W2, xb, Wf1, Wf2, statsp);

  k_conv<true><<<1024, 256, 0, stream>>>(xb, nbr, Wf1, zrow, (void*)h1pre, gsum1, gsq1);
  k_bn_relu<<<2048, 256, 0, stream>>>(h1pre, gsum1, gsq1, g1, b1, h1post);
  k_conv<false><<<1024, 256, 0, stream>>>(h1post, nbr, Wf2, zrow, (void*)h2raw, gsum2, gsq2);

  k_final<<<4096, 256, 0, stream>>>(h2raw, x, gsum2, gsq2, g2, b2, out);
}

// Round 10
// 174.732 us; speedup vs baseline: 1.1505x; 1.1505x over previous
//
#include <hip/hip_runtime.h>

typedef unsigned short ushort_t;
using bf16x8 = __attribute__((ext_vector_type(8))) short;
using f32x16 = __attribute__((ext_vector_type(16))) float;

#define KT 27
#define NV 65536

__device__ inline unsigned short f2bf(float f) {
  unsigned int u = __builtin_bit_cast(unsigned int, f);
  u += 0x7fffu + ((u >> 16) & 1u);
  return (unsigned short)(u >> 16);
}
__device__ inline float b2f(ushort_t u) {
  unsigned int x = ((unsigned int)u) << 16;
  return __builtin_bit_cast(float, x);
}

// compile-time loop: every iteration index is constexpr.
template <int I, int N, typename F>
__device__ __forceinline__ void static_for(F&& f) {
  if constexpr (I < N) {
    f.template operator()<I>();
    static_for<I + 1, N>(static_cast<F&&>(f));
  }
}

// merged prep: statsp+zrow zero (block 0), x fp32->bf16 (blocks 0..4095),
// W1,W2 [k][c][d] -> per-lane MFMA B frags for 32x32x16 (blocks 4096..4959).
// Wf[(k*8 + ks*2 + ct)*512 + l*8 + j] = bf16(W[k][ks*16 + (l>>5)*8 + j][ct*32 + (l&31)])
// (exactly 110592 elems per W -> no OOB W reads, unlike the pre-R7 prep)
__global__ __launch_bounds__(256) void k_prep(const float* __restrict__ x,
                                              const float* __restrict__ W1,
                                              const float* __restrict__ W2,
                                              ushort_t* __restrict__ xb,
                                              ushort_t* __restrict__ Wf1,
                                              ushort_t* __restrict__ Wf2,
                                              float* __restrict__ statsp) {
  int b = blockIdx.x;
  int t = threadIdx.x;
  if (b == 0) {                    // 256 stats floats + 256 floats of zero-row pad
    statsp[t] = 0.f;               // convs run after this dispatch
    statsp[256 + t] = 0.f;         // zrow: gather target for inactive taps
  }
  if (b < 4096) {
    int i = b * 256 + t;  // float4 index
    float4 v = ((const float4*)x)[i];
    ushort4 o;
    o.x = f2bf(v.x); o.y = f2bf(v.y); o.z = f2bf(v.z); o.w = f2bf(v.w);
    ((ushort4*)xb)[i] = o;
  } else {
    int e = (b - 4096) * 256 + t;  // < 221184 = 2 * 110592
    const float* W = W1; ushort_t* Wf = Wf1;
    if (e >= 110592) { e -= 110592; W = W2; Wf = Wf2; }
    int j = e & 7, l = (e >> 3) & 63, u = (e >> 9) & 7, k = e >> 12;  // k < 27
    int ks = u >> 1, ct = u & 1;
    int c = ks * 16 + (l >> 5) * 8 + j;
    int d = ct * 32 + (l & 31);
    Wf[e] = f2bf(W[(k << 12) + (c << 6) + d]);
  }
}

// Gather-GEMM conv, 32x32x16 MFMA.
// R10: TA-segment-throughput attack (model fits R4=47.5us and R9=56us):
//  (1) B (weights) staged in LDS ONCE PER BLOCK in 4-tap phases via
//      global_load_lds (coalesced; 2 instr/wave/tap = 32 segs) instead of
//      every wave re-loading from global (128 segs/tap-wave). ds_read_b128
//      consumption rides the parallel DS pipe, conflict-free (lane*16B).
//  (2) A-gather restored to R0's geometry: 8 lanes cover one row's FULL 128B
//      per instruction (16 segs/instr, the 2-seg/row floor) + per-wave
//      XOR-swizzled LDS A-tile, double-buffered, wave-local (no barriers).
// Ledger: ~96 segs/tap-wave vs R4's 256 -> predict ~25-32us/conv.
// Barriers only at 4-tap phase boundaries (stage visibility), 2 per phase.
// LDS: As 32KB + Bs 32KB + rulebook 13.8KB + red 2KB = 81408B -> 2 blocks/CU.
template<bool OBF16>
__global__ __launch_bounds__(256, 2)
void k_conv(const ushort_t* __restrict__ src,  // [N][64] bf16
            const int* __restrict__ nbr,       // [N][27]
            const ushort_t* __restrict__ Wf,
            const ushort_t* __restrict__ zrow, // 1KB of zeros
            void* __restrict__ houtv,          // [N][64]
            float* __restrict__ gsum,
            float* __restrict__ gsq) {
  __shared__ alignas(16) ushort_t As[4][2][2048];  // per-wave dbuf 32x64 tile, 32 KB
  __shared__ alignas(16) ushort_t Bs[4][4096];     // phase's 4 taps of B frags, 32 KB
  __shared__ int nb_l[4][32 * KT];                 // per-wave rulebook rows, 13.8 KB
  __shared__ float red[2][4][64];                  // stats reduce, 2 KB

  const int t = threadIdx.x;
  const int lane = t & 63;
  const int w = t >> 6;
  const int hh = lane >> 5;
  const int r31 = lane & 31;
  const int wbase = blockIdx.x * 128 + w * 32;

  int* nbw = &nb_l[w][0];
  {
    const int* nbg = nbr + wbase * KT;
    for (int e = lane; e < 32 * KT; e += 64) nbw[e] = nbg[e];  // wave-local
  }

  f32x16 acc0 = {0,0,0,0,0,0,0,0,0,0,0,0,0,0,0,0};
  f32x16 acc1 = {0,0,0,0,0,0,0,0,0,0,0,0,0,0,0,0};

  struct AR { uint4 a, b, c, d; };   // 16 VGPRs, by-value named slots only

  const int srow0 = lane >> 3;       // staging row (+8*i); srow0 < 8
  const int sch = (lane & 7) * 8;    // channel offset (ushorts): 8 lanes span a row's 128B
  const int swz = (lane & 7) ^ srow0; // XOR-swizzled chunk index (row&7 == srow0)

  // A gather for tap k: rows srow0+8i, this lane's 16B chunk of the row.
  auto ldA = [&](int k) -> AR {
    AR r;
    int i0 = nbw[(srow0 +  0) * KT + k];
    int i1 = nbw[(srow0 +  8) * KT + k];
    int i2 = nbw[(srow0 + 16) * KT + k];
    int i3 = nbw[(srow0 + 24) * KT + k];
    const ushort_t* p0 = (i0 >= 0) ? (src + ((long)i0 << 6) + sch) : (zrow + sch);
    const ushort_t* p1 = (i1 >= 0) ? (src + ((long)i1 << 6) + sch) : (zrow + sch);
    const ushort_t* p2 = (i2 >= 0) ? (src + ((long)i2 << 6) + sch) : (zrow + sch);
    const ushort_t* p3 = (i3 >= 0) ? (src + ((long)i3 << 6) + sch) : (zrow + sch);
    r.a = *(const uint4*)p0;
    r.b = *(const uint4*)p1;
    r.c = *(const uint4*)p2;
    r.d = *(const uint4*)p3;
    return r;
  };
  auto wrA = [&](int buf, const AR& r) {
    ushort_t* base = &As[w][buf][0];
    *(uint4*)(base + (srow0 +  0) * 64 + swz * 8) = r.a;
    *(uint4*)(base + (srow0 +  8) * 64 + swz * 8) = r.b;
    *(uint4*)(base + (srow0 + 16) * 64 + swz * 8) = r.c;
    *(uint4*)(base + (srow0 + 24) * 64 + swz * 8) = r.d;
  };
  // stage tap g's B frags (8KB) into Bs[kk]; wave w covers [w*2KB, w*2KB+2KB)
  auto stageB = [&](int g, int kk) {
    const ushort_t* s = Wf + g * 4096 + w * 1024 + lane * 8;  // per-lane global src
    ushort_t* d = &Bs[kk][w * 1024];                          // wave-uniform LDS dst
    __builtin_amdgcn_global_load_lds(
        (const __attribute__((address_space(1))) void*)(s),
        (__attribute__((address_space(3))) void*)(d), 16, 0, 0);
    __builtin_amdgcn_global_load_lds(
        (const __attribute__((address_space(1))) void*)(s + 512),
        (__attribute__((address_space(3))) void*)(d + 512), 16, 0, 0);
  };
  auto computeT = [&](int buf, int kk) {
    const ushort_t* ar = &As[w][buf][r31 * 64];
    const ushort_t* bp = &Bs[kk][lane * 8];
    const int s7 = r31 & 7;
#pragma unroll
    for (int ks = 0; ks < 4; ++ks) {
      bf16x8 af = *(const bf16x8*)(ar + (((ks * 2 + hh) ^ s7) * 8));
      bf16x8 b0 = *(const bf16x8*)(bp + (ks * 2 + 0) * 512);
      bf16x8 b1 = *(const bf16x8*)(bp + (ks * 2 + 1) * 512);
      acc0 = __builtin_amdgcn_mfma_f32_32x32x16_bf16(af, b0, acc0, 0, 0, 0);
      acc1 = __builtin_amdgcn_mfma_f32_32x32x16_bf16(af, b1, acc1, 0, 0, 0);
    }
  };

  // A pipeline (R0 invariant): at iter k, As-buf(k&1)=tap k, RA[(k+1)&1]=tap k+1.
  AR RA0 = ldA(0), RA1 = ldA(1);
  wrA(0, RA0);

  static_for<0, KT>([&]<int k>() {
    if constexpr ((k & 3) == 0) {              // 4-tap phase boundary
      __syncthreads();                         // prior phase's Bs reads done
      constexpr int nt = (KT - k < 4) ? (KT - k) : 4;
      static_for<0, nt>([&]<int kk>() { stageB(k + kk, kk); });
      __syncthreads();                         // staged B visible (vmcnt drained)
    }
    if constexpr (k + 2 < KT) {
      AR tmp = ldA(k + 2);
      if constexpr ((k & 1) == 0) RA0 = tmp; else RA1 = tmp;
    }
    if constexpr (k + 1 < KT) {
      if constexpr (((k + 1) & 1) == 0) wrA((k + 1) & 1, RA0);
      else wrA((k + 1) & 1, RA1);
    }
    computeT(k & 1, k & 3);
  });

  // epilogue: store h + fused per-channel stats
  // C/D (32x32): col = lane&31, row = (reg&3) + 8*(reg>>2) + 4*(lane>>5)
  const int orow0 = wbase + (hh << 2);
  float s0 = 0.f, q0 = 0.f, s1 = 0.f, q1 = 0.f;
#pragma unroll
  for (int reg = 0; reg < 16; ++reg) {
    int row = orow0 + (reg & 3) + 8 * (reg >> 2);
    float v0 = acc0[reg], v1 = acc1[reg];
    if (OBF16) {
      ushort_t* ho = (ushort_t*)houtv;
      ho[row * 64 + r31] = f2bf(v0);
      ho[row * 64 + 32 + r31] = f2bf(v1);
    } else {
      float* ho = (float*)houtv;
      ho[row * 64 + r31] = v0;
      ho[row * 64 + 32 + r31] = v1;
    }
    s0 += v0; q0 += v0 * v0;
    s1 += v1; q1 += v1 * v1;
  }
  s0 += __shfl_xor(s0, 32, 64); q0 += __shfl_xor(q0, 32, 64);
  s1 += __shfl_xor(s1, 32, 64); q1 += __shfl_xor(q1, 32, 64);
  if (hh == 0) {
    red[0][w][r31] = s0; red[0][w][32 + r31] = s1;
    red[1][w][r31] = q0; red[1][w][32 + r31] = q1;
  }
  __syncthreads();
  if (t < 128) {
    int which = t >> 6, c = t & 63;
    float v = red[which][0][c] + red[which][1][c] + red[which][2][c] + red[which][3][c];
    atomicAdd((which ? gsq : gsum) + c, v);
  }
}

// BN1 (inline params from raw stats) + ReLU on bf16 h1, writes bf16 for conv2's gather
__global__ __launch_bounds__(256) void k_bn_relu(const ushort_t* __restrict__ h,
                                                 const float* __restrict__ gsum,
                                                 const float* __restrict__ gsq,
                                                 const float* __restrict__ gamma,
                                                 const float* __restrict__ beta,
                                                 ushort_t* __restrict__ ob) {
  __shared__ float sc[64], sh[64];
  int t = threadIdx.x;
  if (t < 64) {
    float mean = gsum[t] * (1.f / NV);
    float var = gsq[t] * (1.f / NV) - mean * mean;
    float rs = rsqrtf(var + 1e-5f);
    float s = gamma[t] * rs;
    sc[t] = s;
    sh[t] = beta[t] - mean * s;
  }
  __syncthreads();
  int i = blockIdx.x * 256 + t;    // uint4 index = 8 bf16
  int c0 = (i & 7) * 8;
  uint4 v = ((const uint4*)h)[i];
  const ushort_t* pu = (const ushort_t*)&v;
  uint4 o;
  ushort_t* po = (ushort_t*)&o;
#pragma unroll
  for (int n = 0; n < 8; ++n)
    po[n] = f2bf(fmaxf(0.f, b2f(pu[n]) * sc[c0 + n] + sh[c0 + n]));
  ((uint4*)ob)[i] = o;
}

// BN2 (inline params) + residual + ReLU, fp32 out
__global__ __launch_bounds__(256) void k_final(const float* __restrict__ h,
                                               const float* __restrict__ x,
                                               const float* __restrict__ gsum,
                                               const float* __restrict__ gsq,
                                               const float* __restrict__ gamma,
                                               const float* __restrict__ beta,
                                               float* __restrict__ out) {
  __shared__ float sc[64], sh[64];
  int t = threadIdx.x;
  if (t < 64) {
    float mean = gsum[t] * (1.f / NV);
    float var = gsq[t] * (1.f / NV) - mean * mean;
    float rs = rsqrtf(var + 1e-5f);
    float s = gamma[t] * rs;
    sc[t] = s;
    sh[t] = beta[t] - mean * s;
  }
  __syncthreads();
  int i = blockIdx.x * 256 + t;
  int c0 = (i << 2) & 63;
  float4 v = ((const float4*)h)[i];
  float4 xv = ((const float4*)x)[i];
  float4 o;
  o.x = fmaxf(0.f, v.x * sc[c0]     + sh[c0]     + xv.x);
  o.y = fmaxf(0.f, v.y * sc[c0 + 1] + sh[c0 + 1] + xv.y);
  o.z = fmaxf(0.f, v.z * sc[c0 + 2] + sh[c0 + 2] + xv.z);
  o.w = fmaxf(0.f, v.w * sc[c0 + 3] + sh[c0 + 3] + xv.w);
  ((float4*)out)[i] = o;
}

extern "C" void kernel_launch(void* const* d_in, const int* in_sizes, int n_in,
                              void* d_out, int out_size, void* d_ws, size_t ws_size,
                              hipStream_t stream) {
  const float* x   = (const float*)d_in[0];
  const int*   nbr = (const int*)d_in[1];
  const float* W1  = (const float*)d_in[2];
  const float* g1  = (const float*)d_in[3];
  const float* b1  = (const float*)d_in[4];
  const float* W2  = (const float*)d_in[5];
  const float* g2  = (const float*)d_in[6];
  const float* b2  = (const float*)d_in[7];
  float* out = (float*)d_out;
  char* ws = (char*)d_ws;

  // workspace layout (bytes, 256-aligned), total ~42.8 MB (+2KB stats/zero pad)
  ushort_t* xb     = (ushort_t*)(ws);               // 8,388,608
  ushort_t* h1pre  = (ushort_t*)(ws + 8388608);     // 8,388,608 (bf16, pre-BN)
  ushort_t* h1post = (ushort_t*)(ws + 16777216);    // 8,388,608 (bf16, post-BN+ReLU)
  ushort_t* Wf1    = (ushort_t*)(ws + 25165824);    // 221,184 used
  ushort_t* Wf2    = (ushort_t*)(ws + 25608192);    // 221,184 used
  float*    h2raw  = (float*)(ws + 26050560);       // 16,777,216
  float*    statsp = (float*)(ws + 42827776);       // 512 floats (stats + zero row)
  float *gsum1 = statsp, *gsq1 = statsp + 64, *gsum2 = statsp + 128, *gsq2 = statsp + 192;
  const ushort_t* zrow = (const ushort_t*)(statsp + 256);  // 1KB of zeros

  k_prep<<<4960, 256, 0, stream>>>(x, W1, W2, xb, Wf1, Wf2, statsp);

  k_conv<true><<<512, 256, 0, stream>>>(xb, nbr, Wf1, zrow, (void*)h1pre, gsum1, gsq1);
  k_bn_relu<<<2048, 256, 0, stream>>>(h1pre, gsum1, gsq1, g1, b1, h1post);
  k_conv<false><<<512, 256, 0, stream>>>(h1post, nbr, Wf2, zrow, (void*)h2raw, gsum2, gsq2);

  k_final<<<4096, 256, 0, stream>>>(h2raw, x, gsum2, gsq2, g2, b2, out);
}